// Round 9
// baseline (130.026 us; speedup 1.0000x reference)
//
#include <hip/hip_runtime.h>
#include <hip/hip_fp16.h>

// Problem constants
#define N_VISITS   16384
#define MAX_CODES  64
#define DIM        64
#define NUM_CODES  100000
#define NSLICES    8
#define SLICE_ROWS 12500    // 8 * 12500 = 100000 exactly
#define SLICE_F4   100000   // 16B elems per fp16 slice: 12500*64*2/16
#define PER_BLK    391      // ceil(SLICE_F4 / 256)

typedef float f32x4 __attribute__((ext_vector_type(4)));
typedef float f32x2 __attribute__((ext_vector_type(2)));

// ---------------------------------------------------------------------------
// Kernel A: XCD-partitioned fp32->fp16 convert. Block b (on XCD b%8 under
// round-robin dispatch) converts slice s = b&7 (12500 rows = 1.6 MB fp16).
// PLAIN stores: the slice allocates in the local L2 and stays resident
// (clean after end-of-kernel writeback — R5 proved cache lines survive
// kernel boundaries). nt loads keep the 25.6 MB fp32 source from evicting
// the freshly written slice. grid 2048 = 256 blocks per slice.
// ---------------------------------------------------------------------------
__global__ __launch_bounds__(256) void emb_to_half_xcd_kernel(
    const float* __restrict__ emb, __half* __restrict__ embh)
{
    const int s = blockIdx.x & 7;     // slice == intended XCD
    const int q = blockIdx.x >> 3;    // 0..255 within slice
    #pragma unroll
    for (int it = 0; it < 2; ++it) {
        const int local = (int)threadIdx.x + it * 256;
        if (local >= PER_BLK) break;
        const int k = q * PER_BLK + local;
        if (k >= SLICE_F4) break;
        const f32x4* src = (const f32x4*)emb + (size_t)s * (2 * SLICE_F4) + 2 * (size_t)k;
        f32x4 a = __builtin_nontemporal_load(src);
        f32x4 b = __builtin_nontemporal_load(src + 1);
        union { __half2 h[4]; f32x4 f; } u;
        u.h[0] = __floats2half2_rn(a.x, a.y);
        u.h[1] = __floats2half2_rn(a.z, a.w);
        u.h[2] = __floats2half2_rn(b.x, b.y);
        u.h[3] = __floats2half2_rn(b.z, b.w);
        ((f32x4*)embh)[(size_t)s * SLICE_F4 + k] = u.f;   // PLAIN store -> L2 resident
    }
}

// ---------------------------------------------------------------------------
// Kernel B: 8-slice XCD-partitioned LEAN gather. Block b: slice p = b&7
// (constant per XCD), visit group g = b>>3, one wave per (visit, slice).
// E[8 of 64] in-range ids, ballot-compacted to LDS (intra-wave, no barrier
// — validated R4-R6); ~2 gathers of 4 rows x (16 lanes x 8B), ~100% local
// L2 hits if the convert's residency held. Pre-scaled fp16 partial (128B)
// nt-stored. Coverage of all 8 slices per visit is combinatorial —
// correctness never depends on the block->XCD mapping.
// ---------------------------------------------------------------------------
__global__ __launch_bounds__(256) void gather8_partial_kernel(
    const int* __restrict__ code_ids,
    const __half* __restrict__ embh,
    __half* __restrict__ partials)
{
    __shared__ int slots[4][64];

    const int w    = threadIdx.x >> 6;
    const int lane = threadIdx.x & 63;
    const int p    = blockIdx.x & 7;        // slice (constant per XCD)
    const int g    = blockIdx.x >> 3;       // visit group
    const int visit = g * 4 + w;
    const int lo = p * SLICE_ROWS;
    const int hi = lo + SLICE_ROWS;

    const int r = lane >> 4;   // row slot (0..3)
    const int t = lane & 15;   // 8B chunk of the 128B row (0..15)

    // ids re-read by 8 slice-blocks: nt keeps them out of L2 so the table
    // slice owns it.
    const int my_id = __builtin_nontemporal_load(
        code_ids + (size_t)visit * MAX_CODES + lane);

    const unsigned long long vmask = __ballot(my_id >= 0);
    const int total = __popcll(vmask);

    const bool inr = (my_id >= lo) && (my_id < hi);
    const unsigned long long rmask = __ballot(inr);
    const int nrows = __popcll(rmask);
    const int rank  = __popcll(rmask & ((1ull << lane) - 1ull));
    if (inr) slots[w][rank] = my_id;

    const int ngather = (nrows + 3) >> 2;

    float acc[4] = {0.f, 0.f, 0.f, 0.f};
    for (int j = 0; j < ngather; ++j) {
        const int sidx = 4 * j + r;
        if (sidx < nrows) {                  // uniform per 16-lane row group
            const int id = slots[w][sidx];
            union { f32x2 f; __half2 h[2]; } u;
            u.f = *(const f32x2*)(embh + (size_t)id * DIM + t * 4);  // local L2
            const float2 f0 = __half22float2(u.h[0]);
            const float2 f1 = __half22float2(u.h[1]);
            acc[0] += f0.x; acc[1] += f0.y;
            acc[2] += f1.x; acc[3] += f1.y;
        }
    }

    // Reduce the 4 row-slots (lanes t, t+16, t+32, t+48): 2 stages x 4 floats
    #pragma unroll
    for (int k = 0; k < 4; ++k) acc[k] += __shfl_xor(acc[k], 16, 64);
    #pragma unroll
    for (int k = 0; k < 4; ++k) acc[k] += __shfl_xor(acc[k], 32, 64);

    if (lane < 16) {
        const float scale = (total > 0) ? (1.0f / (float)total) : 0.0f;
        union { __half2 h[2]; f32x2 f; } o;
        o.h[0] = __floats2half2_rn(acc[0] * scale, acc[1] * scale);
        o.h[1] = __floats2half2_rn(acc[2] * scale, acc[3] * scale);
        // 16 lanes x 8B = 128B fp16 pre-scaled partial row; nt store.
        __builtin_nontemporal_store(
            o.f, (f32x2*)(partials + ((size_t)visit * NSLICES + p) * DIM) + t);
    }
}

// ---------------------------------------------------------------------------
// Kernel C: sum the 8 fp16 pre-scaled partials per visit -> fp32 out.
// Streaming: 16 MB read + 4 MB write ~= 3-4 us. One f32x4 of out per thread.
// ---------------------------------------------------------------------------
__global__ __launch_bounds__(256) void reduce8_kernel(
    const __half* __restrict__ partials, float* __restrict__ out)
{
    const int i = blockIdx.x * 256 + threadIdx.x;   // 0..262143 f32x4 chunks
    const int visit = i >> 4;
    const int c     = i & 15;                       // 4-dim chunk of the row

    const __half* base = partials + (size_t)visit * NSLICES * DIM + c * 4;
    float a0 = 0.f, a1 = 0.f, a2 = 0.f, a3 = 0.f;
    #pragma unroll
    for (int p = 0; p < NSLICES; ++p) {
        union { f32x2 f; __half2 h[2]; } u;
        u.f = __builtin_nontemporal_load((const f32x2*)(base + (size_t)p * DIM));
        const float2 f0 = __half22float2(u.h[0]);
        const float2 f1 = __half22float2(u.h[1]);
        a0 += f0.x; a1 += f0.y; a2 += f1.x; a3 += f1.y;
    }
    f32x4 o; o.x = a0; o.y = a1; o.z = a2; o.w = a3;
    __builtin_nontemporal_store(o, (f32x4*)out + i);
}

extern "C" void kernel_launch(void* const* d_in, const int* in_sizes, int n_in,
                              void* d_out, int out_size, void* d_ws, size_t ws_size,
                              hipStream_t stream) {
    const int*   code_ids = (const int*)d_in[0];    // [N_VISITS, MAX_CODES] int32
    const float* emb      = (const float*)d_in[1];  // [NUM_CODES, DIM] fp32
    float*       out      = (float*)d_out;          // [N_VISITS, DIM] fp32

    __half* embh = (__half*)d_ws;                          // 12.8 MB fp16 table
    __half* ph   = (__half*)((char*)d_ws + (16u << 20));   // 16 MB fp16 partials

    // A: XCD-partitioned convert — each XCD's L2 ends holding its 1.6 MB slice
    emb_to_half_xcd_kernel<<<2048, 256, 0, stream>>>(emb, embh);

    // B: 8-slice partitioned gather -> fp16 pre-scaled partials
    // grid = (16384/4 visit groups) * 8 slices = 32768 blocks
    gather8_partial_kernel<<<32768, 256, 0, stream>>>(code_ids, embh, ph);

    // C: reduce 8 partials -> out (262144 f32x4 chunks)
    reduce8_kernel<<<1024, 256, 0, stream>>>(ph, out);
}

// Round 10
// 100.181 us; speedup vs baseline: 1.2979x; 1.2979x over previous
//
#include <hip/hip_runtime.h>
#include <hip/hip_fp16.h>

// Problem constants
#define N_VISITS  16384
#define MAX_CODES 64
#define DIM       64
#define NUM_CODES 100000

typedef float f32x4 __attribute__((ext_vector_type(4)));

// ---------------------------------------------------------------------------
// Kernel A: convert emb table fp32 -> fp16 (12.8 MB). Byte-identical to R8.
// One f32x4 of output per thread, exact grid 3125x256. nt loads + nt stores.
// ---------------------------------------------------------------------------
__global__ __launch_bounds__(256) void emb_to_half_kernel(
    const float* __restrict__ emb, __half* __restrict__ embh)
{
    const size_t i = (size_t)blockIdx.x * 256 + threadIdx.x;   // 0..799999
    const f32x4* src = (const f32x4*)emb + 2 * i;
    f32x4 a = __builtin_nontemporal_load(src);
    f32x4 b = __builtin_nontemporal_load(src + 1);
    union { __half2 h[4]; f32x4 f; } u;
    u.h[0] = __floats2half2_rn(a.x, a.y);
    u.h[1] = __floats2half2_rn(a.z, a.w);
    u.h[2] = __floats2half2_rn(b.x, b.y);
    u.h[3] = __floats2half2_rn(b.z, b.w);
    __builtin_nontemporal_store(u.f, (f32x4*)embh + i);
}

// ---------------------------------------------------------------------------
// Kernel W: RANDOM-ORDER warm pass (single-variable change vs R8's
// sequential warm, which was null). Reads every table row exactly once but
// in permuted order, using the gather's exact request shape: one wave-wide
// f32x4 load touches 8 scattered 128B rows. Theory: memory-side caches
// stream-detect sequential reads and bypass installs (R8 null), while
// random 128B requests install (R5: gather-after-gather ran 16 us vs 40).
// row = k*31013 mod 100000 is a bijection (gcd=1); k in [0,100096) covers
// all rows. ~12.8 MB of requests, ~4-6 us. asm sink prevents DCE.
// Correctness does not depend on this kernel.
// ---------------------------------------------------------------------------
__global__ __launch_bounds__(256) void table_warm_rand_kernel(
    const __half* __restrict__ embh)
{
    const unsigned wave = (blockIdx.x * 256u + threadIdx.x) >> 6;  // 0..1563
    const unsigned lane = threadIdx.x & 63u;
    const unsigned r = lane >> 3;   // row slot within each load (0..7)
    const unsigned t = lane & 7;    // 16B chunk of the 128B row

    #pragma unroll
    for (unsigned j = 0; j < 8; ++j) {
        const unsigned k   = wave * 64u + j * 8u + r;        // < 100096
        const unsigned row = (k * 31013u) % 100000u;         // bijective perm
        f32x4 v = *((const f32x4*)(embh + (size_t)row * DIM) + t);
        asm volatile("" :: "v"(v.x), "v"(v.y), "v"(v.z), "v"(v.w));
    }
}

// ---------------------------------------------------------------------------
// Kernel B: monolithic gather + masked mean (byte-identical to R2/R7/R8).
// One wave per visit. r = lane>>3 (8 row slots), t = lane&7 (16B chunk of
// the 128B fp16 row). All 8 gathers (1 KB per wave instruction) issued
// before any accumulation.
// ---------------------------------------------------------------------------
__global__ __launch_bounds__(256) void visit_mean_kernel(
    const int* __restrict__ code_ids,
    const __half* __restrict__ embh,
    float* __restrict__ out)
{
    const int wave_in_block = threadIdx.x >> 6;
    const int lane = threadIdx.x & 63;
    const int visit = blockIdx.x * 4 + wave_in_block;

    const int r = lane >> 3;
    const int t = lane & 7;

    const int my_id = __builtin_nontemporal_load(
        code_ids + (size_t)visit * MAX_CODES + lane);
    const unsigned long long valid = __ballot(my_id >= 0);
    const int count = __popcll(valid);

    int ids[8];
    #pragma unroll
    for (int j = 0; j < 8; ++j) ids[j] = __shfl(my_id, 8 * j + r, 64);

    f32x4 v[8];
    #pragma unroll
    for (int j = 0; j < 8; ++j) {
        const int id   = ids[j];
        const int safe = (id >= 0) ? id : 0;
        v[j] = *((const f32x4*)(embh + (size_t)safe * DIM) + t);
    }

    float acc[8] = {0.f,0.f,0.f,0.f,0.f,0.f,0.f,0.f};
    #pragma unroll
    for (int j = 0; j < 8; ++j) {
        const float m = (ids[j] >= 0) ? 1.0f : 0.0f;
        const __half2* h = (const __half2*)&v[j];
        #pragma unroll
        for (int k = 0; k < 4; ++k) {
            const float2 f = __half22float2(h[k]);
            acc[2 * k]     = fmaf(m, f.x, acc[2 * k]);
            acc[2 * k + 1] = fmaf(m, f.y, acc[2 * k + 1]);
        }
    }

    #pragma unroll
    for (int k = 0; k < 8; ++k) acc[k] += __shfl_xor(acc[k], 8, 64);
    #pragma unroll
    for (int k = 0; k < 8; ++k) acc[k] += __shfl_xor(acc[k], 16, 64);
    #pragma unroll
    for (int k = 0; k < 8; ++k) acc[k] += __shfl_xor(acc[k], 32, 64);

    if (lane < 8) {
        const float scale = (count > 0) ? (1.0f / (float)count) : 0.0f;
        f32x4 o0, o1;
        o0.x = acc[0] * scale; o0.y = acc[1] * scale;
        o0.z = acc[2] * scale; o0.w = acc[3] * scale;
        o1.x = acc[4] * scale; o1.y = acc[5] * scale;
        o1.z = acc[6] * scale; o1.w = acc[7] * scale;
        f32x4* dst = (f32x4*)(out + (size_t)visit * DIM + lane * 8);
        __builtin_nontemporal_store(o0, dst);
        __builtin_nontemporal_store(o1, dst + 1);
    }
}

extern "C" void kernel_launch(void* const* d_in, const int* in_sizes, int n_in,
                              void* d_out, int out_size, void* d_ws, size_t ws_size,
                              hipStream_t stream) {
    const int*   code_ids = (const int*)d_in[0];    // [N_VISITS, MAX_CODES] int32
    const float* emb      = (const float*)d_in[1];  // [NUM_CODES, DIM] fp32
    float*       out      = (float*)d_out;          // [N_VISITS, DIM] fp32
    __half*      embh     = (__half*)d_ws;          // 12.8 MB fp16 table

    // A: fp32 -> fp16 table
    emb_to_half_kernel<<<3125, 256, 0, stream>>>(emb, embh);

    // W: random-order warm — install table lines via random 128B requests
    // 1564 waves = 391 blocks x 4 waves; covers all 100000 rows once
    table_warm_rand_kernel<<<391, 256, 0, stream>>>(embh);

    // B: monolithic gather + masked mean, one wave per visit
    visit_mean_kernel<<<4096, 256, 0, stream>>>(code_ids, embh, out);
}